// Round 5
// baseline (204.646 us; speedup 1.0000x reference)
//
#include <hip/hip_runtime.h>

// Problem constants
constexpr int B_ = 32, C_ = 64, H_ = 64, W_ = 64, K_ = 1024;
constexpr int NTOT = B_ * C_ * H_ * W_;          // 8388608 elements of input1/quantized
constexpr int NSP  = B_ * H_ * W_;               // 131072 spatial positions
// d_out float offsets: [0]=loss, [1..32]=input2_KL, [33..33+NTOT)=quantized(BCHW),
// [OFF_ENC .. OFF_ENC+NSP*K)=encodings
constexpr int OFF_Q   = 33;
constexpr int OFF_ENC = OFF_Q + NTOT;            // 8388641  (byte addr == 4 mod 16)
constexpr long long ENC_ELEMS = (long long)NSP * K_;   // 134217728 (2^27)
// Aligned interior: first aligned element e0=3 (dword OFF_ENC+3 is 16B aligned),
// (ENC_ELEMS-4)/4 float4 groups; 3 head + 1 tail elements handled scalar in vq_fin.
constexpr int ENC_NV4 = (int)((ENC_ELEMS - 4) / 4);    // 33554431 groups

typedef float v4f __attribute__((ext_vector_type(4)));  // native vec for nontemporal

// Main fused kernel: gather codebook rows, write quantized (BCHW), accumulate loss.
__global__ __launch_bounds__(256) void vq_main(const float* __restrict__ input1,
                                               const int*   __restrict__ x_tilde,
                                               const float* __restrict__ weight,
                                               float* __restrict__ out,   // d_out base
                                               float* __restrict__ acc) { // d_ws accumulator
    float local = 0.f;
    const int stride = gridDim.x * blockDim.x;
    constexpr int NG = NTOT / 4;
    for (int g = blockIdx.x * blockDim.x + threadIdx.x; g < NG; g += stride) {
        const int f  = g << 2;
        const int b  = f >> 18;          // C*H*W = 2^18
        const int c  = (f >> 12) & 63;   // H*W   = 2^12
        const int n0 = (b << 12) | (f & 4095);   // spatial index, multiple of 4
        const int4   t4 = *reinterpret_cast<const int4*>(x_tilde + n0);
        const float4 x4 = *reinterpret_cast<const float4*>(input1 + f);
        const float q0 = weight[(t4.x << 6) | c];
        const float q1 = weight[(t4.y << 6) | c];
        const float q2 = weight[(t4.z << 6) | c];
        const float q3 = weight[(t4.w << 6) | c];
        const float d0 = q0 - x4.x, d1 = q1 - x4.y, d2 = q2 - x4.z, d3 = q3 - x4.w;
        out[OFF_Q + f + 0] = x4.x + d0;  // straight-through: x + (q - x)
        out[OFF_Q + f + 1] = x4.y + d1;
        out[OFF_Q + f + 2] = x4.z + d2;
        out[OFF_Q + f + 3] = x4.w + d3;
        local += d0 * d0 + d1 * d1 + d2 * d2 + d3 * d3;
    }
    // wave64 reduce
    for (int o = 32; o > 0; o >>= 1) local += __shfl_down(local, o);
    __shared__ float sm[4];
    const int lane = threadIdx.x & 63, wid = threadIdx.x >> 6;
    if (lane == 0) sm[wid] = local;
    __syncthreads();
    if (threadIdx.x == 0) {
        atomicAdd(acc, sm[0] + sm[1] + sm[2] + sm[3]);
    }
}

// Fused one-hot fill: writes the entire encodings interior (zeros AND ones) with
// aligned nontemporal 16B stores. No memset, no scatter RMW pass.
__global__ __launch_bounds__(256) void vq_enc_fill(const int* __restrict__ x_tilde,
                                                   float* __restrict__ out) {
    const int stride = gridDim.x * blockDim.x;
    for (int g = blockIdx.x * blockDim.x + threadIdx.x; g < ENC_NV4; g += stride) {
        const int e0 = (g << 2) + 3;          // element index within encodings (16B aligned)
        const int n  = e0 >> 10;              // row
        const int k0 = e0 & 1023;             // col of first element
        const int t  = x_tilde[n];            // broadcast within 256-thread runs
        v4f v;
        if (k0 != 1023) {                     // whole quad inside row n (255/256 case)
            v.x = (t == k0    ) ? 1.f : 0.f;
            v.y = (t == k0 + 1) ? 1.f : 0.f;
            v.z = (t == k0 + 2) ? 1.f : 0.f;
            v.w = (t == k0 + 3) ? 1.f : 0.f;
        } else {                              // quad straddles rows n / n+1
            const int t1 = x_tilde[n + 1];
            v.x = (t  == 1023) ? 1.f : 0.f;
            v.y = (t1 == 0   ) ? 1.f : 0.f;
            v.z = (t1 == 1   ) ? 1.f : 0.f;
            v.w = (t1 == 2   ) ? 1.f : 0.f;
        }
        __builtin_nontemporal_store(v, reinterpret_cast<v4f*>(out + OFF_ENC + e0));
    }
}

// Finalize: loss scalar, input2_KL passthrough, and the 4 edge elements the
// aligned fill skipped (cols 0..2 of row 0; col 1023 of the last row).
__global__ void vq_fin(const int* __restrict__ x_tilde,
                       const float* __restrict__ acc,
                       const float* __restrict__ kl,
                       float* __restrict__ out) {
    const int t = threadIdx.x;
    if (t < 32) out[1 + t] = kl[t];
    if (t == 32) out[0] = 1.25f * (*acc) / (float)NTOT;
    if (t == 33) {
        const int t0 = x_tilde[0];
        out[OFF_ENC + 0] = (t0 == 0) ? 1.f : 0.f;
        out[OFF_ENC + 1] = (t0 == 1) ? 1.f : 0.f;
        out[OFF_ENC + 2] = (t0 == 2) ? 1.f : 0.f;
        const int tl = x_tilde[NSP - 1];
        out[OFF_ENC + (int)ENC_ELEMS - 1] = (tl == 1023) ? 1.f : 0.f;
    }
}

extern "C" void kernel_launch(void* const* d_in, const int* in_sizes, int n_in,
                              void* d_out, int out_size, void* d_ws, size_t ws_size,
                              hipStream_t stream) {
    const float* input1 = (const float*)d_in[0];
    const float* kl     = (const float*)d_in[1];
    const float* weight = (const float*)d_in[2];
    const int*   x_til  = (const int*)d_in[3];
    float* out = (float*)d_out;
    float* acc = (float*)d_ws;

    (void)hipMemsetAsync(acc, 0, sizeof(float), stream);

    vq_main<<<2048, 256, 0, stream>>>(input1, x_til, weight, out, acc);
    vq_enc_fill<<<2048, 256, 0, stream>>>(x_til, out);
    vq_fin<<<1, 64, 0, stream>>>(x_til, acc, kl, out);
}